// Round 1
// baseline (8749.815 us; speedup 1.0000x reference)
//
#include <hip/hip_runtime.h>

#define N_NODES 100000
#define N_EDGES 3200000
#define N_GRAPHS 4096
#define IN_DIM 74
#define HID 64
#define MLP_HID 128

// ---- projection: xw = x@W ; res = relu(x@R + rb). One thread per (node, f).
template<int IN>
__global__ void proj_kernel(const float* __restrict__ x,
                            const float* __restrict__ W,
                            const float* __restrict__ R,
                            const float* __restrict__ rb,
                            float* __restrict__ xw,
                            float* __restrict__ res,
                            int n_nodes) {
    int t = blockIdx.x * blockDim.x + threadIdx.x;
    int n = t >> 6;
    int f = t & 63;
    if (n >= n_nodes) return;
    const float* xr = x + (long)n * IN;
    float accW = 0.f, accR = 0.f;
    #pragma unroll 8
    for (int k = 0; k < IN; ++k) {
        float xv = xr[k];
        accW += xv * W[k * HID + f];
        accR += xv * R[k * HID + f];
    }
    xw[(long)n * HID + f] = accW;
    res[(long)n * HID + f] = fmaxf(accR + rb[f], 0.f);
}

// ---- edge scatter: agg[dst] += xw[src]; 16 lanes (float4 each) per edge.
__global__ void scatter_kernel(const float* __restrict__ xw,
                               const int* __restrict__ src,
                               const int* __restrict__ dst,
                               float* __restrict__ agg,
                               int n_edges) {
    long t = (long)blockIdx.x * blockDim.x + threadIdx.x;
    int e = (int)(t >> 4);
    int p = (int)(t & 15);
    if (e >= n_edges) return;
    int s = src[e];
    int d = dst[e];
    const float4 v = *reinterpret_cast<const float4*>(xw + (long)s * HID + p * 4);
    float* o = agg + (long)d * HID + p * 4;
    atomicAdd(o + 0, v.x);
    atomicAdd(o + 1, v.y);
    atomicAdd(o + 2, v.z);
    atomicAdd(o + 3, v.w);
}

// ---- finish: xout = relu(agg + b) + res
__global__ void finish_kernel(const float* __restrict__ agg,
                              const float* __restrict__ b,
                              const float* __restrict__ res,
                              float* __restrict__ xout,
                              int total) {
    int t = blockIdx.x * blockDim.x + threadIdx.x;
    if (t >= total) return;
    int f = t & 63;
    xout[t] = fmaxf(agg[t] + b[f], 0.f) + res[t];
}

// ---- pooling: g[graph_ids[n]] += x[n]; 16 lanes (float4) per node.
__global__ void pool_kernel(const float* __restrict__ x,
                            const int* __restrict__ gid,
                            float* __restrict__ g,
                            int n_nodes) {
    long t = (long)blockIdx.x * blockDim.x + threadIdx.x;
    int n = (int)(t >> 4);
    int p = (int)(t & 15);
    if (n >= n_nodes) return;
    int gi = gid[n];
    const float4 v = *reinterpret_cast<const float4*>(x + (long)n * HID + p * 4);
    float* o = g + (long)gi * HID + p * 4;
    atomicAdd(o + 0, v.x);
    atomicAdd(o + 1, v.y);
    atomicAdd(o + 2, v.z);
    atomicAdd(o + 3, v.w);
}

// ---- MLP: one wave per graph. out = relu(g@Wm1+bm1) @ Wm2 + bm2
__global__ void mlp_kernel(const float* __restrict__ g,
                           const float* __restrict__ Wm1,
                           const float* __restrict__ bm1,
                           const float* __restrict__ Wm2,
                           const float* __restrict__ bm2,
                           float* __restrict__ out,
                           int n_graphs) {
    int wid = (blockIdx.x * blockDim.x + threadIdx.x) >> 6;
    int lane = threadIdx.x & 63;
    if (wid >= n_graphs) return;
    const float* gr = g + (long)wid * HID;
    float h0 = bm1[lane];
    float h1 = bm1[lane + 64];
    for (int k = 0; k < HID; ++k) {
        float gv = gr[k];
        h0 += gv * Wm1[k * MLP_HID + lane];
        h1 += gv * Wm1[k * MLP_HID + lane + 64];
    }
    float part = fmaxf(h0, 0.f) * Wm2[lane] + fmaxf(h1, 0.f) * Wm2[lane + 64];
    #pragma unroll
    for (int off = 32; off > 0; off >>= 1)
        part += __shfl_down(part, off, 64);
    if (lane == 0) out[wid] = part + bm2[0];
}

extern "C" void kernel_launch(void* const* d_in, const int* in_sizes, int n_in,
                              void* d_out, int out_size, void* d_ws, size_t ws_size,
                              hipStream_t stream) {
    const float* feats = (const float*)d_in[0];
    const int*   src   = (const int*)d_in[1];
    const int*   dst   = (const int*)d_in[2];
    const int*   gid   = (const int*)d_in[3];
    const float* W[3]  = {(const float*)d_in[4],  (const float*)d_in[8],  (const float*)d_in[12]};
    const float* b[3]  = {(const float*)d_in[5],  (const float*)d_in[9],  (const float*)d_in[13]};
    const float* R[3]  = {(const float*)d_in[6],  (const float*)d_in[10], (const float*)d_in[14]};
    const float* rb[3] = {(const float*)d_in[7],  (const float*)d_in[11], (const float*)d_in[15]};
    const float* Wm1 = (const float*)d_in[16];
    const float* bm1 = (const float*)d_in[17];
    const float* Wm2 = (const float*)d_in[18];
    const float* bm2 = (const float*)d_in[19];
    float* out = (float*)d_out;

    // workspace carve
    char* ws = (char*)d_ws;
    const size_t node_buf = (size_t)N_NODES * HID * sizeof(float); // 25.6 MB
    float* xbuf = (float*)(ws);
    float* xw   = (float*)(ws + node_buf);
    float* res  = (float*)(ws + 2 * node_buf);
    float* agg  = (float*)(ws + 3 * node_buf);
    float* g    = (float*)(ws + 4 * node_buf);  // 4096*64*4 = 1 MB

    const int total = N_NODES * HID;

    for (int l = 0; l < 3; ++l) {
        const float* xin = (l == 0) ? feats : xbuf;
        // projections
        {
            int threads = N_NODES * HID;
            int blocks = (threads + 255) / 256;
            if (l == 0)
                proj_kernel<IN_DIM><<<blocks, 256, 0, stream>>>(xin, W[l], R[l], rb[l], xw, res, N_NODES);
            else
                proj_kernel<HID><<<blocks, 256, 0, stream>>>(xin, W[l], R[l], rb[l], xw, res, N_NODES);
        }
        // zero agg
        hipMemsetAsync(agg, 0, node_buf, stream);
        // scatter
        {
            long threads = (long)N_EDGES * 16;
            int blocks = (int)((threads + 255) / 256);
            scatter_kernel<<<blocks, 256, 0, stream>>>(xw, src, dst, agg, N_EDGES);
        }
        // finish
        {
            int blocks = (total + 255) / 256;
            finish_kernel<<<blocks, 256, 0, stream>>>(agg, b[l], res, xbuf, total);
        }
    }

    // pooling
    hipMemsetAsync(g, 0, (size_t)N_GRAPHS * HID * sizeof(float), stream);
    {
        long threads = (long)N_NODES * 16;
        int blocks = (int)((threads + 255) / 256);
        pool_kernel<<<blocks, 256, 0, stream>>>(xbuf, gid, g, N_NODES);
    }
    // MLP
    {
        int threads = N_GRAPHS * 64;
        int blocks = (threads + 255) / 256;
        mlp_kernel<<<blocks, 256, 0, stream>>>(g, Wm1, bm1, Wm2, bm2, out, N_GRAPHS);
    }
}

// Round 2
// 1437.191 us; speedup vs baseline: 6.0881x; 6.0881x over previous
//
#include <hip/hip_runtime.h>

#define N_NODES 100000
#define N_EDGES 3200000
#define N_GRAPHS 4096
#define IN_DIM 74
#define HID 64
#define MLP_HID 128

// ---- projection: xw = x@W ; res = relu(x@R + rb). One thread per (node, f).
template<int IN>
__global__ void proj_kernel(const float* __restrict__ x,
                            const float* __restrict__ W,
                            const float* __restrict__ R,
                            const float* __restrict__ rb,
                            float* __restrict__ xw,
                            float* __restrict__ res,
                            int n_nodes) {
    int t = blockIdx.x * blockDim.x + threadIdx.x;
    int n = t >> 6;
    int f = t & 63;
    if (n >= n_nodes) return;
    const float* xr = x + (long)n * IN;
    float accW = 0.f, accR = 0.f;
    #pragma unroll 8
    for (int k = 0; k < IN; ++k) {
        float xv = xr[k];
        accW += xv * W[k * HID + f];
        accR += xv * R[k * HID + f];
    }
    xw[(long)n * HID + f] = accW;
    res[(long)n * HID + f] = fmaxf(accR + rb[f], 0.f);
}

// ---- CSR build step 1: histogram of dst
__global__ void hist_kernel(const int* __restrict__ dst, int* __restrict__ deg,
                            int n_edges) {
    int e = blockIdx.x * blockDim.x + threadIdx.x;
    if (e >= n_edges) return;
    atomicAdd(&deg[dst[e]], 1);
}

// ---- CSR build step 2: exclusive scan (single block, 1024 threads)
__global__ void scan_kernel(const int* __restrict__ deg, int* __restrict__ row_ptr) {
    __shared__ int sdata[1024];
    __shared__ int running;
    int tid = threadIdx.x;
    if (tid == 0) running = 0;
    __syncthreads();
    for (int base = 0; base < N_NODES; base += 1024) {
        int i = base + tid;
        int v = (i < N_NODES) ? deg[i] : 0;
        int r = running;
        sdata[tid] = v;
        __syncthreads();
        for (int off = 1; off < 1024; off <<= 1) {
            int t = (tid >= off) ? sdata[tid - off] : 0;
            __syncthreads();
            sdata[tid] += t;
            __syncthreads();
        }
        int incl = sdata[tid];
        if (i < N_NODES) row_ptr[i] = r + incl - v;
        __syncthreads();
        if (tid == 0) running = r + sdata[1023];
        __syncthreads();
    }
    if (tid == 0) row_ptr[N_NODES] = running;
}

// ---- CSR build step 3: fill (cursor pre-copied from row_ptr)
__global__ void fill_kernel(const int* __restrict__ src, const int* __restrict__ dst,
                            int* __restrict__ cursor, int* __restrict__ csr_src,
                            int n_edges) {
    int e = blockIdx.x * blockDim.x + threadIdx.x;
    if (e >= n_edges) return;
    int d = dst[e];
    int pos = atomicAdd(&cursor[d], 1);
    csr_src[pos] = src[e];
}

// ---- gather aggregation + epilogue: one wave per node, lane = feature.
// xout[n] = relu(sum_{s in in(n)} xw[s] + b) + res[n]
__global__ void gather_kernel(const float* __restrict__ xw,
                              const int* __restrict__ row_ptr,
                              const int* __restrict__ csr_src,
                              const float* __restrict__ b,
                              const float* __restrict__ res,
                              float* __restrict__ xout,
                              int n_nodes) {
    int wid = (blockIdx.x * blockDim.x + threadIdx.x) >> 6;
    int lane = threadIdx.x & 63;
    if (wid >= n_nodes) return;
    int start = row_ptr[wid];
    int end = row_ptr[wid + 1];
    float acc = 0.f;
    int e = start;
    for (; e + 4 <= end; e += 4) {
        int s0 = csr_src[e];
        int s1 = csr_src[e + 1];
        int s2 = csr_src[e + 2];
        int s3 = csr_src[e + 3];
        float v0 = xw[(long)s0 * HID + lane];
        float v1 = xw[(long)s1 * HID + lane];
        float v2 = xw[(long)s2 * HID + lane];
        float v3 = xw[(long)s3 * HID + lane];
        acc += (v0 + v1) + (v2 + v3);
    }
    for (; e < end; ++e)
        acc += xw[(long)csr_src[e] * HID + lane];
    long o = (long)wid * HID + lane;
    xout[o] = fmaxf(acc + b[lane], 0.f) + res[o];
}

// ---- pooling gather: graph_ids sorted -> binary search range, one wave/graph
__global__ void pool_gather_kernel(const float* __restrict__ x,
                                   const int* __restrict__ gid,
                                   float* __restrict__ g,
                                   int n_graphs) {
    int wid = (blockIdx.x * blockDim.x + threadIdx.x) >> 6;
    int lane = threadIdx.x & 63;
    if (wid >= n_graphs) return;
    // lower_bound(wid)
    int lo = 0, hi = N_NODES;
    while (lo < hi) { int mid = (lo + hi) >> 1; if (gid[mid] < wid) lo = mid + 1; else hi = mid; }
    int start = lo;
    hi = N_NODES;
    while (lo < hi) { int mid = (lo + hi) >> 1; if (gid[mid] < wid + 1) lo = mid + 1; else hi = mid; }
    int end = lo;
    float acc = 0.f;
    for (int n = start; n < end; ++n)
        acc += x[(long)n * HID + lane];
    g[(long)wid * HID + lane] = acc;
}

// ---- MLP: one wave per graph. out = relu(g@Wm1+bm1) @ Wm2 + bm2
__global__ void mlp_kernel(const float* __restrict__ g,
                           const float* __restrict__ Wm1,
                           const float* __restrict__ bm1,
                           const float* __restrict__ Wm2,
                           const float* __restrict__ bm2,
                           float* __restrict__ out,
                           int n_graphs) {
    int wid = (blockIdx.x * blockDim.x + threadIdx.x) >> 6;
    int lane = threadIdx.x & 63;
    if (wid >= n_graphs) return;
    const float* gr = g + (long)wid * HID;
    float h0 = bm1[lane];
    float h1 = bm1[lane + 64];
    for (int k = 0; k < HID; ++k) {
        float gv = gr[k];
        h0 += gv * Wm1[k * MLP_HID + lane];
        h1 += gv * Wm1[k * MLP_HID + lane + 64];
    }
    float part = fmaxf(h0, 0.f) * Wm2[lane] + fmaxf(h1, 0.f) * Wm2[lane + 64];
    #pragma unroll
    for (int off = 32; off > 0; off >>= 1)
        part += __shfl_down(part, off, 64);
    if (lane == 0) out[wid] = part + bm2[0];
}

extern "C" void kernel_launch(void* const* d_in, const int* in_sizes, int n_in,
                              void* d_out, int out_size, void* d_ws, size_t ws_size,
                              hipStream_t stream) {
    const float* feats = (const float*)d_in[0];
    const int*   src   = (const int*)d_in[1];
    const int*   dst   = (const int*)d_in[2];
    const int*   gid   = (const int*)d_in[3];
    const float* W[3]  = {(const float*)d_in[4],  (const float*)d_in[8],  (const float*)d_in[12]};
    const float* b[3]  = {(const float*)d_in[5],  (const float*)d_in[9],  (const float*)d_in[13]};
    const float* R[3]  = {(const float*)d_in[6],  (const float*)d_in[10], (const float*)d_in[14]};
    const float* rb[3] = {(const float*)d_in[7],  (const float*)d_in[11], (const float*)d_in[15]};
    const float* Wm1 = (const float*)d_in[16];
    const float* bm1 = (const float*)d_in[17];
    const float* Wm2 = (const float*)d_in[18];
    const float* bm2 = (const float*)d_in[19];
    float* out = (float*)d_out;

    // workspace carve
    char* ws = (char*)d_ws;
    const size_t node_buf = (size_t)N_NODES * HID * sizeof(float);   // 25.6 MB
    float* xbuf    = (float*)(ws);                      ws += node_buf;
    float* xw      = (float*)(ws);                      ws += node_buf;
    float* res     = (float*)(ws);                      ws += node_buf;
    float* gbuf    = (float*)(ws);                      ws += (size_t)N_GRAPHS * HID * sizeof(float);
    int*   deg     = (int*)(ws);                        ws += (size_t)(N_NODES + 1) * sizeof(int);
    int*   row_ptr = (int*)(ws);                        ws += (size_t)(N_NODES + 1) * sizeof(int);
    int*   cursor  = (int*)(ws);                        ws += (size_t)(N_NODES + 1) * sizeof(int);
    int*   csr_src = (int*)(ws);                        ws += (size_t)N_EDGES * sizeof(int);

    // ---- build CSR (by dst) once
    hipMemsetAsync(deg, 0, (size_t)(N_NODES + 1) * sizeof(int), stream);
    hist_kernel<<<(N_EDGES + 255) / 256, 256, 0, stream>>>(dst, deg, N_EDGES);
    scan_kernel<<<1, 1024, 0, stream>>>(deg, row_ptr);
    hipMemcpyAsync(cursor, row_ptr, (size_t)(N_NODES + 1) * sizeof(int),
                   hipMemcpyDeviceToDevice, stream);
    fill_kernel<<<(N_EDGES + 255) / 256, 256, 0, stream>>>(src, dst, cursor, csr_src, N_EDGES);

    const int total = N_NODES * HID;

    for (int l = 0; l < 3; ++l) {
        const float* xin = (l == 0) ? feats : xbuf;
        {
            int blocks = (total + 255) / 256;
            if (l == 0)
                proj_kernel<IN_DIM><<<blocks, 256, 0, stream>>>(xin, W[l], R[l], rb[l], xw, res, N_NODES);
            else
                proj_kernel<HID><<<blocks, 256, 0, stream>>>(xin, W[l], R[l], rb[l], xw, res, N_NODES);
        }
        {
            int blocks = (total + 255) / 256;  // one wave (64 threads) per node
            gather_kernel<<<blocks, 256, 0, stream>>>(xw, row_ptr, csr_src, b[l], res, xbuf, N_NODES);
        }
    }

    // pooling (gather over sorted graph_ids)
    {
        int threads = N_GRAPHS * 64;
        pool_gather_kernel<<<(threads + 255) / 256, 256, 0, stream>>>(xbuf, gid, gbuf, N_GRAPHS);
    }
    // MLP
    {
        int threads = N_GRAPHS * 64;
        mlp_kernel<<<(threads + 255) / 256, 256, 0, stream>>>(gbuf, Wm1, bm1, Wm2, bm2, out, N_GRAPHS);
    }
}